// Round 3
// baseline (323.139 us; speedup 1.0000x reference)
//
#include <hip/hip_runtime.h>
#include <math.h>
#include <float.h>

#define BN 32
#define CH 3
#define HH 512
#define WW 512
#define NP 4
#define EPS 128
#define HALF 64
#define MARGIN 32

#define PATCH_ELEMS (BN * NP * CH * EPS * EPS)   // 6291456
#define NT 4096          // 64x64 grid of 8x8 tiles
#define TPR 64           // tiles per row

// ---------------------------------------------------------------------------
// Selection: one block of 1024 threads per map. Tile cache lives in LDS.
// Build (registers) -> 4x [block argmax -> box -> incremental tile update].
// ---------------------------------------------------------------------------
__global__ __launch_bounds__(1024)
void select_kernel(const float* __restrict__ umaps,
                   float* __restrict__ coords_out,
                   int* __restrict__ coords_ws)
{
    const int b    = blockIdx.x;
    const int tid  = threadIdx.x;
    const int lane = tid & 63;
    const int wave = tid >> 6;
    const float* __restrict__ um = umaps + (size_t)b * HH * WW;

    __shared__ float tv[NT];
    __shared__ int   ti[NT];
    __shared__ int   boxes[NP][4];   // clipped, margin-expanded ex1,ex2,ey1,ey2
    __shared__ float rv[16];
    __shared__ int   ri[16];

    // ---- build per-tile argmax, 4 tiles/thread, all in registers ----
    #pragma unroll
    for (int i = 0; i < 4; ++i) {
        const int t  = tid + (i << 10);
        const int tx = t & (TPR - 1), ty = t >> 6;
        const int x0 = tx << 3, y0 = ty << 3;
        float bv = -INFINITY; int bi = 0x7fffffff;
        #pragma unroll
        for (int r = 0; r < 8; ++r) {
            const int rowbase = (y0 + r) * WW + x0;
            const float4 a = *(const float4*)(um + rowbase);
            const float4 c = *(const float4*)(um + rowbase + 4);
            float vals[8] = {a.x, a.y, a.z, a.w, c.x, c.y, c.z, c.w};
            #pragma unroll
            for (int j = 0; j < 8; ++j)
                if (vals[j] > bv) { bv = vals[j]; bi = rowbase + j; }  // ascending idx => first-max
        }
        tv[t] = bv; ti[t] = bi;
    }
    __syncthreads();

    for (int k = 0; k < NP; ++k) {
        // ---- block argmax over 4096 tile entries ----
        float bv = -INFINITY; int bi = 0x7fffffff;
        #pragma unroll
        for (int i = 0; i < 4; ++i) {
            const float v = tv[tid + (i << 10)];
            const int   x = ti[tid + (i << 10)];
            if (v > bv || (v == bv && x < bi)) { bv = v; bi = x; }
        }
        #pragma unroll
        for (int off = 32; off > 0; off >>= 1) {
            float ov = __shfl_down(bv, off);
            int   oi = __shfl_down(bi, off);
            if (ov > bv || (ov == bv && oi < bi)) { bv = ov; bi = oi; }
        }
        if (lane == 0) { rv[wave] = bv; ri[wave] = bi; }
        __syncthreads();

        if (tid == 0) {
            bv = rv[0]; bi = ri[0];
            #pragma unroll
            for (int w = 1; w < 16; ++w)
                if (rv[w] > bv || (rv[w] == bv && ri[w] < bi)) { bv = rv[w]; bi = ri[w]; }
            const int yc = bi >> 9, xc = bi & 511;
            int x1 = max(0, xc - HALF), x2 = min(WW, xc + HALF);
            int y1 = max(0, yc - HALF), y2 = min(HH, yc + HALF);
            if (x2 - x1 < EPS) { if (x1 == 0) x2 = EPS; else x1 = x2 - EPS; }
            if (y2 - y1 < EPS) { if (y1 == 0) y2 = EPS; else y1 = y2 - EPS; }
            boxes[k][0] = max(x1 - MARGIN, 0);
            boxes[k][1] = min(x2 + MARGIN, WW);
            boxes[k][2] = max(y1 - MARGIN, 0);
            boxes[k][3] = min(y2 + MARGIN, HH);

            const int o = (b * NP + k) * 4;
            coords_out[o + 0] = (float)x1;
            coords_out[o + 1] = (float)y1;
            coords_out[o + 2] = (float)x2;
            coords_out[o + 3] = (float)y2;
            coords_ws[(b * NP + k) * 2 + 0] = x1;
            coords_ws[(b * NP + k) * 2 + 1] = y1;
        }
        __syncthreads();

        if (k == NP - 1) break;

        // ---- incremental tile update for the NEW box ----
        const int ex1 = boxes[k][0], ex2 = boxes[k][1];
        const int ey1 = boxes[k][2], ey2 = boxes[k][3];
        #pragma unroll
        for (int i = 0; i < 4; ++i) {
            const int t  = tid + (i << 10);
            const int tx = t & (TPR - 1), ty = t >> 6;
            const int X1 = tx << 3, Y1 = ty << 3;
            const int X2 = X1 + 8,  Y2 = Y1 + 8;
            if (X1 >= ex2 || X2 <= ex1 || Y1 >= ey2 || Y2 <= ey1) continue;  // untouched
            if (X1 >= ex1 && X2 <= ex2 && Y1 >= ey1 && Y2 <= ey2) {          // fully suppressed
                tv[t] = -INFINITY; ti[t] = 0x7fffffff; continue;
            }
            // perimeter tile: rescan 64 px in registers vs all boxes so far
            float nv = -INFINITY; int ni = 0x7fffffff;
            #pragma unroll
            for (int r = 0; r < 8; ++r) {
                const int y = Y1 + r;
                const int rowbase = y * WW + X1;
                const float4 a = *(const float4*)(um + rowbase);
                const float4 c = *(const float4*)(um + rowbase + 4);
                float vals[8] = {a.x, a.y, a.z, a.w, c.x, c.y, c.z, c.w};
                #pragma unroll
                for (int j = 0; j < 8; ++j) {
                    const int xe = X1 + j;
                    bool m = false;
                    for (int jb = 0; jb <= k; ++jb)
                        m |= (y  >= boxes[jb][2]) & (y  < boxes[jb][3]) &
                             (xe >= boxes[jb][0]) & (xe < boxes[jb][1]);
                    if (!m && vals[j] > nv) { nv = vals[j]; ni = rowbase + j; }
                }
            }
            tv[t] = nv; ti[t] = ni;
        }
        __syncthreads();
    }
}

// ---------------------------------------------------------------------------
// Patch gather. 4 px per thread, float4 stores.
// ---------------------------------------------------------------------------
__global__ __launch_bounds__(256)
void extract_kernel(const float* __restrict__ images,
                    const int* __restrict__ coords_ws,
                    float4* __restrict__ out4)
{
    const int i4   = blockIdx.x * 256 + threadIdx.x;   // < PATCH_ELEMS/4
    const int px0  = (i4 & 31) << 2;
    const int py   = (i4 >> 5) & 127;
    const int rest = i4 >> 12;           // b*NP*CH + n*CH + c
    const int c    = rest % CH;
    const int bn   = rest / CH;
    const int b    = bn >> 2;

    const int x1 = coords_ws[bn * 2 + 0];
    const int y1 = coords_ws[bn * 2 + 1];

    const float* __restrict__ src =
        images + (((size_t)b * CH + c) * HH + (y1 + py)) * WW + x1 + px0;
    out4[i4] = make_float4(src[0], src[1], src[2], src[3]);
}

extern "C" void kernel_launch(void* const* d_in, const int* in_sizes, int n_in,
                              void* d_out, int out_size, void* d_ws, size_t ws_size,
                              hipStream_t stream) {
    const float* images = (const float*)d_in[0];
    const float* umaps  = (const float*)d_in[1];
    float* out          = (float*)d_out;
    int*   coords_ws    = (int*)d_ws;     // 256 ints

    float* coords_out = out + PATCH_ELEMS;

    select_kernel<<<BN, 1024, 0, stream>>>(umaps, coords_out, coords_ws);
    extract_kernel<<<PATCH_ELEMS / 4 / 256, 256, 0, stream>>>(images, coords_ws, (float4*)out);
}